// Round 5
// baseline (1256.807 us; speedup 1.0000x reference)
//
#include <hip/hip_runtime.h>
#include <hip/hip_bf16.h>
#include <cstdint>
#include <cstddef>

typedef __attribute__((ext_vector_type(8))) short short8;
typedef __attribute__((ext_vector_type(4))) float float4v;

#define L_SEQ 2048
#define N_B   4
#define E_DIM 2048
#define N_H   16
#define H_D   128
// (1/sqrt(128)) * log2(e)
#define C1_SCALE_LOG2E 0.12751744f

static __device__ __forceinline__ unsigned short f2bf(float f) {
  union { float f; unsigned int u; } x; x.f = f;
  unsigned int u = x.u;
  u = u + 0x7fffu + ((u >> 16) & 1u);   // round-to-nearest-even
  return (unsigned short)(u >> 16);
}

static __device__ __forceinline__ void g2l16(const void* g, void* l) {
  __builtin_amdgcn_global_load_lds(
      (const __attribute__((address_space(1))) unsigned int*)g,
      (__attribute__((address_space(3))) unsigned int*)l, 16, 0, 0);
}

// ---------------- fp32 -> bf16 conversion (8 elems/thread) ----------------
__global__ __launch_bounds__(256) void cvt_kernel(const float* __restrict__ in,
                                                  unsigned short* __restrict__ out,
                                                  int n8) {
  int i = blockIdx.x * blockDim.x + threadIdx.x;
  if (i >= n8) return;
  const float4* p = (const float4*)in;
  float4 a = p[2 * i];
  float4 b = p[2 * i + 1];
  short8 o;
  o[0] = (short)f2bf(a.x); o[1] = (short)f2bf(a.y);
  o[2] = (short)f2bf(a.z); o[3] = (short)f2bf(a.w);
  o[4] = (short)f2bf(b.x); o[5] = (short)f2bf(b.y);
  o[6] = (short)f2bf(b.z); o[7] = (short)f2bf(b.w);
  *(short8*)(out + 8 * (size_t)i) = o;
}

// ---------------- GEMM: C[m,n] = sum_k A[m,k]*B[n,k] + bias[n] --------------
// M=8192 rows (m = l*N_B + n_batch), Ncol=K=2048. 128x128 tile, BK=32.
// MODE 0: fp32 row-major out. MODE 1: bf16 (n,h,l,d). MODE 2: bf16 (n,h,d,l).
template <int MODE>
__global__ __launch_bounds__(256) void gemm_bt(const unsigned short* __restrict__ A,
                                               const unsigned short* __restrict__ B,
                                               const float* __restrict__ bias,
                                               void* __restrict__ Cout) {
  __shared__ unsigned short sA[128 * 32];
  __shared__ unsigned short sB[128 * 32];
  const int tid = threadIdx.x;
  const int wv = tid >> 6, ln = tid & 63;
  const int wr = wv >> 1, wc = wv & 1;
  const int lhi = ln >> 4, llo = ln & 15;
  const int kr = lhi * 8;
  const int m0 = blockIdx.y * 128, n0 = blockIdx.x * 128;

  float4v acc[4][4] = {};

  const char* Ab = (const char*)A;
  const char* Bb = (const char*)B;
  const int srow = wv * 16 + (ln >> 2);   // staging row within 64-row half
  const int scb  = (ln & 3) * 16;         // staging byte within 64B row

  for (int k0 = 0; k0 < E_DIM; k0 += 32) {
#pragma unroll
    for (int c = 0; c < 2; ++c) {
      g2l16(Ab + ((size_t)(m0 + c * 64 + srow) * E_DIM + k0) * 2 + scb,
            (char*)sA + c * 4096 + wv * 1024);
      g2l16(Bb + ((size_t)(n0 + c * 64 + srow) * E_DIM + k0) * 2 + scb,
            (char*)sB + c * 4096 + wv * 1024);
    }
    __syncthreads();
    short8 af[4], bfr[4];
#pragma unroll
    for (int i = 0; i < 4; ++i)
      af[i] = *(const short8*)(sA + (wr * 64 + i * 16 + llo) * 32 + kr);
#pragma unroll
    for (int jx = 0; jx < 4; ++jx)
      bfr[jx] = *(const short8*)(sB + (wc * 64 + jx * 16 + llo) * 32 + kr);
#pragma unroll
    for (int i = 0; i < 4; ++i)
#pragma unroll
      for (int jx = 0; jx < 4; ++jx)
        acc[i][jx] = __builtin_amdgcn_mfma_f32_16x16x32_bf16(af[i], bfr[jx], acc[i][jx], 0, 0, 0);
    __syncthreads();
  }

  float bcol[4];
#pragma unroll
  for (int jx = 0; jx < 4; ++jx) bcol[jx] = bias[n0 + wc * 64 + jx * 16 + llo];

#pragma unroll
  for (int i = 0; i < 4; ++i) {
#pragma unroll
    for (int r = 0; r < 4; ++r) {
      const int m = m0 + wr * 64 + i * 16 + lhi * 4 + r;
      const int l = m >> 2, nb = m & 3;
#pragma unroll
      for (int jx = 0; jx < 4; ++jx) {
        const int cN = n0 + wc * 64 + jx * 16 + llo;
        const float v = acc[i][jx][r] + bcol[jx];
        if (MODE == 0) {
          ((float*)Cout)[(size_t)m * E_DIM + cN] = v;
        } else if (MODE == 1) {
          const int h = cN >> 7, d = cN & 127;
          ((unsigned short*)Cout)[(((size_t)(nb * N_H + h)) * L_SEQ + l) * H_D + d] = f2bf(v);
        } else {
          const int h = cN >> 7, d = cN & 127;
          ((unsigned short*)Cout)[(((size_t)(nb * N_H + h)) * H_D + d) * L_SEQ + l] = f2bf(v);
        }
      }
    }
  }
}

// ---------------- flash attention (causal), BM=BN=128, 512 threads ---------
// Q,K: (n,h,l,d) bf16.  VT: (n,h,d,l) bf16.  Cc out: (l*N_B+n, h*128+d) bf16.
// 8 waves; wave wv owns Q-rows [wv*16, wv*16+16).
// ROUND-2 LESSON: every loop bound must be compile-time and every accumulator
// index constant -- a runtime `jjmax` bound made s[8] dynamically indexed and
// cost ~2350 VALU instr/wave-iter (10x) in select-waterfalls.  All loops here
// are #pragma unroll with constant trip counts; diagonal masking sits under a
// block-uniform `if (diag)`.
// __launch_bounds__(512,4): cap VGPR at 128 so 2 blocks/CU stay resident
// (LDS 64 KiB allows 2).  Watch WRITE_SIZE ~32.7 MB: growth = spill signature.
// LDS tiles XOR-swizzled in 16B units: chunk u of row r stored at slot u^(r&7).
__global__ __launch_bounds__(512, 4) void flash_attn(const unsigned short* __restrict__ Q,
                                                     const unsigned short* __restrict__ K,
                                                     const unsigned short* __restrict__ VT,
                                                     unsigned short* __restrict__ Cc) {
  __shared__ unsigned short sK[128 * 128];  // K tile -> P tile -> O tile
  __shared__ unsigned short sV[128 * 128];  // V^T tile (d, key)
  const int tid = threadIdx.x;
  const int wv = tid >> 6, ln = tid & 63;
  const int lhi = ln >> 4, llo = ln & 15;
  const int kr = lhi * 8;
  const int tq = (int)gridDim.x - 1 - (int)blockIdx.x;  // heavy blocks first
  const int nh = blockIdx.y;
  const size_t hoff = (size_t)nh * (L_SEQ * H_D);
  const unsigned short* Qp = Q + hoff;
  const char* Kb = (const char*)(K + hoff);
  const char* Vb = (const char*)(VT + hoff);

  // Q fragments: A-operand rows = wv*16 + llo, k = kk*32 + lhi*8
  short8 qf[4];
#pragma unroll
  for (int kk = 0; kk < 4; ++kk)
    qf[kk] = *(const short8*)(Qp + (size_t)(tq * 128 + wv * 16 + llo) * H_D + kk * 32 + kr);

  float4v o_acc[8] = {};
  float mst[4], lst[4];
#pragma unroll
  for (int r = 0; r < 4; ++r) { mst[r] = -1e30f; lst[r] = 0.f; }

  for (int j = 0; j <= tq; ++j) {
    // ---- stage K,V (64 KB): 4 insts each per thread; 4 rows/wave-inst ----
#pragma unroll
    for (int t = 0; t < 4; ++t) {
      const int row = wv * 16 + t * 4 + lhi;
      const int sc = llo ^ (row & 7);
      g2l16(Kb + ((size_t)(j * 128 + row) * H_D) * 2 + sc * 16,
            (char*)sK + wv * 4096 + t * 1024);
      g2l16(Vb + ((size_t)row * L_SEQ + j * 128) * 2 + sc * 16,
            (char*)sV + wv * 4096 + t * 1024);
    }
    __syncthreads();

    // ---- S = Q K^T : wave's 16 rows x 128 cols (all bounds constant) ----
    float4v s[8] = {};
#pragma unroll
    for (int kk = 0; kk < 4; ++kk) {
      const int u0 = kk * 4 + lhi;
#pragma unroll
      for (int jj = 0; jj < 8; ++jj) {
        const int row = jj * 16 + llo;
        const short8 b = *(const short8*)(sK + row * 128 + (u0 ^ (row & 7)) * 8);
        s[jj] = __builtin_amdgcn_mfma_f32_16x16x32_bf16(qf[kk], b, s[jj], 0, 0, 0);
      }
    }

    // ---- scale; causal mask only on the diagonal tile (uniform branch) --
#pragma unroll
    for (int jj = 0; jj < 8; ++jj)
#pragma unroll
      for (int r = 0; r < 4; ++r)
        s[jj][r] *= C1_SCALE_LOG2E;
    const bool diag = (j == tq);
    if (diag) {
      const int qrow = wv * 16 + lhi * 4;
#pragma unroll
      for (int jj = 0; jj < 8; ++jj) {
        const int c = jj * 16 + llo;
#pragma unroll
        for (int r = 0; r < 4; ++r)
          if (c > qrow + r) s[jj][r] = -1e30f;
      }
    }

    // ---- online softmax (log2 domain) ----------------------------------
    float alpha[4];
#pragma unroll
    for (int r = 0; r < 4; ++r) {
      float rm = fmaxf(fmaxf(fmaxf(s[0][r], s[1][r]), fmaxf(s[2][r], s[3][r])),
                       fmaxf(fmaxf(s[4][r], s[5][r]), fmaxf(s[6][r], s[7][r])));
      rm = fmaxf(rm, __shfl_xor(rm, 1, 64));
      rm = fmaxf(rm, __shfl_xor(rm, 2, 64));
      rm = fmaxf(rm, __shfl_xor(rm, 4, 64));
      rm = fmaxf(rm, __shfl_xor(rm, 8, 64));
      const float mnew = fmaxf(mst[r], rm);
      const float a = __builtin_exp2f(mst[r] - mnew);
      mst[r] = mnew;
      alpha[r] = a;
      float rs = 0.f;
#pragma unroll
      for (int jj = 0; jj < 8; ++jj) {
        const float pv = __builtin_exp2f(s[jj][r] - mnew);
        s[jj][r] = pv;
        rs += pv;
      }
      rs += __shfl_xor(rs, 1, 64);
      rs += __shfl_xor(rs, 2, 64);
      rs += __shfl_xor(rs, 4, 64);
      rs += __shfl_xor(rs, 8, 64);
      lst[r] = lst[r] * a + rs;
    }

    __syncthreads();  // all waves done reading K tile (B-frags span all rows)

    // ---- P (bf16, packed b32) into sK, same swizzle --------------------
#pragma unroll
    for (int r = 0; r < 4; ++r) {
      const int rl = wv * 16 + lhi * 4 + r;
#pragma unroll
      for (int jj = 0; jj < 8; ++jj) {
        const int c = jj * 16 + llo;
        const float v = s[jj][r];
        const float v2 = __shfl_xor(v, 1, 64);
        if ((llo & 1) == 0) {
          const unsigned int pk = (unsigned int)f2bf(v) | ((unsigned int)f2bf(v2) << 16);
          const int u = ((c >> 3) ^ (rl & 7));
          *(unsigned int*)(sK + rl * 128 + u * 8 + (c & 7)) = pk;
        }
      }
    }
    // no barrier: PV A-frags read only this wave's own P rows

    // ---- O = O*alpha + P V ---------------------------------------------
#pragma unroll
    for (int jj = 0; jj < 8; ++jj) {
      float4v t = o_acc[jj];
      t[0] *= alpha[0]; t[1] *= alpha[1];
      t[2] *= alpha[2]; t[3] *= alpha[3];
      o_acc[jj] = t;
    }
#pragma unroll
    for (int kk = 0; kk < 4; ++kk) {
      const int u0 = kk * 4 + lhi;
      const int rowp = wv * 16 + llo;
      const short8 a = *(const short8*)(sK + rowp * 128 + (u0 ^ (rowp & 7)) * 8);
#pragma unroll
      for (int jj = 0; jj < 8; ++jj) {
        const int row = jj * 16 + llo;
        const short8 b = *(const short8*)(sV + row * 128 + (u0 ^ (row & 7)) * 8);
        o_acc[jj] = __builtin_amdgcn_mfma_f32_16x16x32_bf16(a, b, o_acc[jj], 0, 0, 0);
      }
    }
    __syncthreads();  // before next iteration's staging overwrites sK/sV
  }

  // ---- epilogue: O /= l, bounce through LDS for coalesced 16B stores -----
  const int nb = nh >> 4, h = nh & 15;
#pragma unroll
  for (int r = 0; r < 4; ++r) {
    const float inv = 1.0f / lst[r];
    const int rl = wv * 16 + lhi * 4 + r;
#pragma unroll
    for (int jj = 0; jj < 8; ++jj) {
      const int c = jj * 16 + llo;
      const float v = o_acc[jj][r] * inv;
      const float v2 = __shfl_xor(v, 1, 64);
      if ((llo & 1) == 0) {
        const unsigned int pk = (unsigned int)f2bf(v) | ((unsigned int)f2bf(v2) << 16);
        *(unsigned int*)(sK + rl * 128 + c) = pk;  // plain layout
      }
    }
  }
  __syncthreads();
#pragma unroll
  for (int t = 0; t < 4; ++t) {
    const int row = wv * 16 + t * 4 + lhi;
    const short8 val = *(const short8*)(sK + row * 128 + llo * 8);
    const int qg = tq * 128 + row;
    *(short8*)(Cc + ((size_t)qg * N_B + nb) * E_DIM + h * H_D + llo * 8) = val;
  }
}

// ---------------------------------------------------------------------------
extern "C" void kernel_launch(void* const* d_in, const int* in_sizes, int n_in,
                              void* d_out, int out_size, void* d_ws, size_t ws_size,
                              hipStream_t stream) {
  (void)in_sizes; (void)n_in; (void)out_size; (void)ws_size;
  const float* query = (const float*)d_in[0];
  const float* key   = (const float*)d_in[1];
  const float* wq = (const float*)d_in[2];
  const float* bq = (const float*)d_in[3];
  const float* wk = (const float*)d_in[4];
  const float* bk = (const float*)d_in[5];
  const float* wv = (const float*)d_in[6];
  const float* bv = (const float*)d_in[7];
  const float* wo = (const float*)d_in[8];
  const float* bo = (const float*)d_in[9];

  char* ws = (char*)d_ws;
  unsigned short* Xq = (unsigned short*)(ws);               // 32 MiB
  unsigned short* Xk = (unsigned short*)(ws + 33554432);    // 32 MiB
  unsigned short* Wq = (unsigned short*)(ws + 67108864);    // 8 MiB
  unsigned short* Wk = (unsigned short*)(ws + 75497472);
  unsigned short* Wv = (unsigned short*)(ws + 83886080);
  unsigned short* Wo = (unsigned short*)(ws + 92274688);
  unsigned short* Qh = (unsigned short*)(ws + 100663296);   // 32 MiB (n,h,l,d)
  unsigned short* Kh = (unsigned short*)(ws + 134217728);   // 32 MiB (n,h,l,d)
  unsigned short* VT = (unsigned short*)(ws + 167772160);   // 32 MiB (n,h,d,l)
  unsigned short* Cc = Xq;  // context aliases Xq (Xq dead after Q-projection)

  const int nAct8 = L_SEQ * N_B * E_DIM / 8;  // 2,097,152
  const int nW8   = E_DIM * E_DIM / 8;        //   524,288
  cvt_kernel<<<dim3((nAct8 + 255) / 256), 256, 0, stream>>>(query, Xq, nAct8);
  cvt_kernel<<<dim3((nAct8 + 255) / 256), 256, 0, stream>>>(key, Xk, nAct8);
  cvt_kernel<<<dim3((nW8 + 255) / 256), 256, 0, stream>>>(wq, Wq, nW8);
  cvt_kernel<<<dim3((nW8 + 255) / 256), 256, 0, stream>>>(wk, Wk, nW8);
  cvt_kernel<<<dim3((nW8 + 255) / 256), 256, 0, stream>>>(wv, Wv, nW8);
  cvt_kernel<<<dim3((nW8 + 255) / 256), 256, 0, stream>>>(wo, Wo, nW8);

  dim3 gg(E_DIM / 128, (L_SEQ * N_B) / 128);  // (16, 64)
  gemm_bt<1><<<gg, 256, 0, stream>>>(Xq, Wq, bq, Qh);
  gemm_bt<1><<<gg, 256, 0, stream>>>(Xk, Wk, bk, Kh);
  gemm_bt<2><<<gg, 256, 0, stream>>>(Xk, Wv, bv, VT);

  flash_attn<<<dim3(L_SEQ / 128, N_B * N_H), 512, 0, stream>>>(Qh, Kh, VT, Cc);

  gemm_bt<0><<<gg, 256, 0, stream>>>(Cc, Wo, bo, d_out);
}

// Round 6
// 887.886 us; speedup vs baseline: 1.4155x; 1.4155x over previous
//
#include <hip/hip_runtime.h>
#include <hip/hip_bf16.h>
#include <cstdint>
#include <cstddef>

typedef __attribute__((ext_vector_type(8))) short short8;
typedef __attribute__((ext_vector_type(4))) float float4v;

#define L_SEQ 2048
#define N_B   4
#define E_DIM 2048
#define N_H   16
#define H_D   128
// (1/sqrt(128)) * log2(e)
#define C1_SCALE_LOG2E 0.12751744f

static __device__ __forceinline__ unsigned short f2bf(float f) {
  union { float f; unsigned int u; } x; x.f = f;
  unsigned int u = x.u;
  u = u + 0x7fffu + ((u >> 16) & 1u);   // round-to-nearest-even
  return (unsigned short)(u >> 16);
}

static __device__ __forceinline__ void g2l16(const void* g, void* l) {
  __builtin_amdgcn_global_load_lds(
      (const __attribute__((address_space(1))) unsigned int*)g,
      (__attribute__((address_space(3))) unsigned int*)l, 16, 0, 0);
}

// ---------------- fp32 -> bf16 conversion (8 elems/thread) ----------------
__global__ __launch_bounds__(256) void cvt_kernel(const float* __restrict__ in,
                                                  unsigned short* __restrict__ out,
                                                  int n8) {
  int i = blockIdx.x * blockDim.x + threadIdx.x;
  if (i >= n8) return;
  const float4* p = (const float4*)in;
  float4 a = p[2 * i];
  float4 b = p[2 * i + 1];
  short8 o;
  o[0] = (short)f2bf(a.x); o[1] = (short)f2bf(a.y);
  o[2] = (short)f2bf(a.z); o[3] = (short)f2bf(a.w);
  o[4] = (short)f2bf(b.x); o[5] = (short)f2bf(b.y);
  o[6] = (short)f2bf(b.z); o[7] = (short)f2bf(b.w);
  *(short8*)(out + 8 * (size_t)i) = o;
}

// ---------------- GEMM: C[m,n] = sum_k A[m,k]*B[n,k] + bias[n] --------------
// M=8192 rows (m = l*N_B + n_batch), Ncol=K=2048. 128x128 tile, BK=32.
// MODE 0: fp32 row-major out. MODE 1: bf16 (n,h,l,d). MODE 2: bf16 (n,h,d,l).
template <int MODE>
__global__ __launch_bounds__(256) void gemm_bt(const unsigned short* __restrict__ A,
                                               const unsigned short* __restrict__ B,
                                               const float* __restrict__ bias,
                                               void* __restrict__ Cout) {
  __shared__ unsigned short sA[128 * 32];
  __shared__ unsigned short sB[128 * 32];
  const int tid = threadIdx.x;
  const int wv = tid >> 6, ln = tid & 63;
  const int wr = wv >> 1, wc = wv & 1;
  const int lhi = ln >> 4, llo = ln & 15;
  const int kr = lhi * 8;
  const int m0 = blockIdx.y * 128, n0 = blockIdx.x * 128;

  float4v acc[4][4] = {};

  const char* Ab = (const char*)A;
  const char* Bb = (const char*)B;
  const int srow = wv * 16 + (ln >> 2);   // staging row within 64-row half
  const int scb  = (ln & 3) * 16;         // staging byte within 64B row

  for (int k0 = 0; k0 < E_DIM; k0 += 32) {
#pragma unroll
    for (int c = 0; c < 2; ++c) {
      g2l16(Ab + ((size_t)(m0 + c * 64 + srow) * E_DIM + k0) * 2 + scb,
            (char*)sA + c * 4096 + wv * 1024);
      g2l16(Bb + ((size_t)(n0 + c * 64 + srow) * E_DIM + k0) * 2 + scb,
            (char*)sB + c * 4096 + wv * 1024);
    }
    __syncthreads();
    short8 af[4], bfr[4];
#pragma unroll
    for (int i = 0; i < 4; ++i)
      af[i] = *(const short8*)(sA + (wr * 64 + i * 16 + llo) * 32 + kr);
#pragma unroll
    for (int jx = 0; jx < 4; ++jx)
      bfr[jx] = *(const short8*)(sB + (wc * 64 + jx * 16 + llo) * 32 + kr);
#pragma unroll
    for (int i = 0; i < 4; ++i)
#pragma unroll
      for (int jx = 0; jx < 4; ++jx)
        acc[i][jx] = __builtin_amdgcn_mfma_f32_16x16x32_bf16(af[i], bfr[jx], acc[i][jx], 0, 0, 0);
    __syncthreads();
  }

  float bcol[4];
#pragma unroll
  for (int jx = 0; jx < 4; ++jx) bcol[jx] = bias[n0 + wc * 64 + jx * 16 + llo];

#pragma unroll
  for (int i = 0; i < 4; ++i) {
#pragma unroll
    for (int r = 0; r < 4; ++r) {
      const int m = m0 + wr * 64 + i * 16 + lhi * 4 + r;
      const int l = m >> 2, nb = m & 3;
#pragma unroll
      for (int jx = 0; jx < 4; ++jx) {
        const int cN = n0 + wc * 64 + jx * 16 + llo;
        const float v = acc[i][jx][r] + bcol[jx];
        if (MODE == 0) {
          ((float*)Cout)[(size_t)m * E_DIM + cN] = v;
        } else if (MODE == 1) {
          const int h = cN >> 7, d = cN & 127;
          ((unsigned short*)Cout)[(((size_t)(nb * N_H + h)) * L_SEQ + l) * H_D + d] = f2bf(v);
        } else {
          const int h = cN >> 7, d = cN & 127;
          ((unsigned short*)Cout)[(((size_t)(nb * N_H + h)) * H_D + d) * L_SEQ + l] = f2bf(v);
        }
      }
    }
  }
}

// ---------------- flash attention (causal), BM=BN=128, 512 threads ---------
// Q,K: (n,h,l,d) bf16.  VT: (n,h,d,l) bf16.  Cc out: (l*N_B+n, h*128+d) bf16.
// 8 waves; wave wv owns Q-rows [wv*16, wv*16+16).
// ROUND-2 LESSON: compile-time loop bounds / constant accumulator indices only
// (runtime bound => select-waterfall, 10x VALU).
// ROUND-5 LESSON: __launch_bounds__(512,4) (128-reg cap) spills ~10 regs/wave
// -> 183 MB surplus WRITE_SIZE.  Live state ~140 unified regs; use (512,2)
// (cap 256, round-2-proven spill-free).  1 block/CU is acceptable once
// staging hits L2 instead of HBM.
// ROUND-5 LESSON 2: FETCH 621 MB == no K/V reuse across Q-blocks (HBM-
// serialized staging ~6.5k cyc/iter vs ~600 cyc MFMA).  Fix: XCD-aware
// 1-D swizzle -- all 16 Q-blocks of one head land on one XCD (lin%8),
// K+V (1 MB/head) stays in that XCD's 4 MB L2.  tq zigzags across head
// groups so per-CU work stays balanced.
// LDS tiles XOR-swizzled in 16B units: chunk u of row r stored at slot u^(r&7).
__global__ __launch_bounds__(512, 2) void flash_attn(const unsigned short* __restrict__ Q,
                                                     const unsigned short* __restrict__ K,
                                                     const unsigned short* __restrict__ VT,
                                                     unsigned short* __restrict__ Cc) {
  __shared__ unsigned short sK[128 * 128];  // K tile -> P tile -> O tile
  __shared__ unsigned short sV[128 * 128];  // V^T tile (d, key)
  const int tid = threadIdx.x;
  const int wv = tid >> 6, ln = tid & 63;
  const int lhi = ln >> 4, llo = ln & 15;
  const int kr = lhi * 8;
  // XCD-locality swizzle: lin -> (xcd, slot); head = hgrp*8 + xcd so a head's
  // 16 Q-blocks share an XCD (dispatch heuristic: block i -> XCD i%8).
  const int lin = (int)blockIdx.x;
  const int xcd = lin & 7, slot = lin >> 3;
  const int hgrp = slot >> 4, pos = slot & 15;
  const int tq = (hgrp & 1) ? (15 - pos) : pos;  // zigzag: balances CU load
  const int nh = hgrp * 8 + xcd;
  const size_t hoff = (size_t)nh * (L_SEQ * H_D);
  const unsigned short* Qp = Q + hoff;
  const char* Kb = (const char*)(K + hoff);
  const char* Vb = (const char*)(VT + hoff);

  // Q fragments: A-operand rows = wv*16 + llo, k = kk*32 + lhi*8
  short8 qf[4];
#pragma unroll
  for (int kk = 0; kk < 4; ++kk)
    qf[kk] = *(const short8*)(Qp + (size_t)(tq * 128 + wv * 16 + llo) * H_D + kk * 32 + kr);

  float4v o_acc[8] = {};
  float mst[4], lst[4];
#pragma unroll
  for (int r = 0; r < 4; ++r) { mst[r] = -1e30f; lst[r] = 0.f; }

  for (int j = 0; j <= tq; ++j) {
    // ---- stage K,V (64 KB): 4 insts each per thread; 4 rows/wave-inst ----
#pragma unroll
    for (int t = 0; t < 4; ++t) {
      const int row = wv * 16 + t * 4 + lhi;
      const int sc = llo ^ (row & 7);
      g2l16(Kb + ((size_t)(j * 128 + row) * H_D) * 2 + sc * 16,
            (char*)sK + wv * 4096 + t * 1024);
      g2l16(Vb + ((size_t)row * L_SEQ + j * 128) * 2 + sc * 16,
            (char*)sV + wv * 4096 + t * 1024);
    }
    __syncthreads();

    // ---- S = Q K^T : wave's 16 rows x 128 cols (all bounds constant) ----
    float4v s[8] = {};
#pragma unroll
    for (int kk = 0; kk < 4; ++kk) {
      const int u0 = kk * 4 + lhi;
#pragma unroll
      for (int jj = 0; jj < 8; ++jj) {
        const int row = jj * 16 + llo;
        const short8 b = *(const short8*)(sK + row * 128 + (u0 ^ (row & 7)) * 8);
        s[jj] = __builtin_amdgcn_mfma_f32_16x16x32_bf16(qf[kk], b, s[jj], 0, 0, 0);
      }
    }

    // ---- scale; causal mask only on the diagonal tile (uniform branch) --
#pragma unroll
    for (int jj = 0; jj < 8; ++jj)
#pragma unroll
      for (int r = 0; r < 4; ++r)
        s[jj][r] *= C1_SCALE_LOG2E;
    const bool diag = (j == tq);
    if (diag) {
      const int qrow = wv * 16 + lhi * 4;
#pragma unroll
      for (int jj = 0; jj < 8; ++jj) {
        const int c = jj * 16 + llo;
#pragma unroll
        for (int r = 0; r < 4; ++r)
          if (c > qrow + r) s[jj][r] = -1e30f;
      }
    }

    // ---- online softmax (log2 domain) ----------------------------------
    float alpha[4];
#pragma unroll
    for (int r = 0; r < 4; ++r) {
      float rm = fmaxf(fmaxf(fmaxf(s[0][r], s[1][r]), fmaxf(s[2][r], s[3][r])),
                       fmaxf(fmaxf(s[4][r], s[5][r]), fmaxf(s[6][r], s[7][r])));
      rm = fmaxf(rm, __shfl_xor(rm, 1, 64));
      rm = fmaxf(rm, __shfl_xor(rm, 2, 64));
      rm = fmaxf(rm, __shfl_xor(rm, 4, 64));
      rm = fmaxf(rm, __shfl_xor(rm, 8, 64));
      const float mnew = fmaxf(mst[r], rm);
      const float a = __builtin_exp2f(mst[r] - mnew);
      mst[r] = mnew;
      alpha[r] = a;
      float rs = 0.f;
#pragma unroll
      for (int jj = 0; jj < 8; ++jj) {
        const float pv = __builtin_exp2f(s[jj][r] - mnew);
        s[jj][r] = pv;
        rs += pv;
      }
      rs += __shfl_xor(rs, 1, 64);
      rs += __shfl_xor(rs, 2, 64);
      rs += __shfl_xor(rs, 4, 64);
      rs += __shfl_xor(rs, 8, 64);
      lst[r] = lst[r] * a + rs;
    }

    __syncthreads();  // all waves done reading K tile (B-frags span all rows)

    // ---- P (bf16, packed b32) into sK, same swizzle --------------------
#pragma unroll
    for (int r = 0; r < 4; ++r) {
      const int rl = wv * 16 + lhi * 4 + r;
#pragma unroll
      for (int jj = 0; jj < 8; ++jj) {
        const int c = jj * 16 + llo;
        const float v = s[jj][r];
        const float v2 = __shfl_xor(v, 1, 64);
        if ((llo & 1) == 0) {
          const unsigned int pk = (unsigned int)f2bf(v) | ((unsigned int)f2bf(v2) << 16);
          const int u = ((c >> 3) ^ (rl & 7));
          *(unsigned int*)(sK + rl * 128 + u * 8 + (c & 7)) = pk;
        }
      }
    }
    // no barrier: PV A-frags read only this wave's own P rows

    // ---- O = O*alpha + P V ---------------------------------------------
#pragma unroll
    for (int jj = 0; jj < 8; ++jj) {
      float4v t = o_acc[jj];
      t[0] *= alpha[0]; t[1] *= alpha[1];
      t[2] *= alpha[2]; t[3] *= alpha[3];
      o_acc[jj] = t;
    }
#pragma unroll
    for (int kk = 0; kk < 4; ++kk) {
      const int u0 = kk * 4 + lhi;
      const int rowp = wv * 16 + llo;
      const short8 a = *(const short8*)(sK + rowp * 128 + (u0 ^ (rowp & 7)) * 8);
#pragma unroll
      for (int jj = 0; jj < 8; ++jj) {
        const int row = jj * 16 + llo;
        const short8 b = *(const short8*)(sV + row * 128 + (u0 ^ (row & 7)) * 8);
        o_acc[jj] = __builtin_amdgcn_mfma_f32_16x16x32_bf16(a, b, o_acc[jj], 0, 0, 0);
      }
    }
    __syncthreads();  // before next iteration's staging overwrites sK/sV
  }

  // ---- epilogue: O /= l, bounce through LDS for coalesced 16B stores -----
  const int nb = nh >> 4, h = nh & 15;
#pragma unroll
  for (int r = 0; r < 4; ++r) {
    const float inv = 1.0f / lst[r];
    const int rl = wv * 16 + lhi * 4 + r;
#pragma unroll
    for (int jj = 0; jj < 8; ++jj) {
      const int c = jj * 16 + llo;
      const float v = o_acc[jj][r] * inv;
      const float v2 = __shfl_xor(v, 1, 64);
      if ((llo & 1) == 0) {
        const unsigned int pk = (unsigned int)f2bf(v) | ((unsigned int)f2bf(v2) << 16);
        *(unsigned int*)(sK + rl * 128 + c) = pk;  // plain layout
      }
    }
  }
  __syncthreads();
#pragma unroll
  for (int t = 0; t < 4; ++t) {
    const int row = wv * 16 + t * 4 + lhi;
    const short8 val = *(const short8*)(sK + row * 128 + llo * 8);
    const int qg = tq * 128 + row;
    *(short8*)(Cc + ((size_t)qg * N_B + nb) * E_DIM + h * H_D + llo * 8) = val;
  }
}

// ---------------------------------------------------------------------------
extern "C" void kernel_launch(void* const* d_in, const int* in_sizes, int n_in,
                              void* d_out, int out_size, void* d_ws, size_t ws_size,
                              hipStream_t stream) {
  (void)in_sizes; (void)n_in; (void)out_size; (void)ws_size;
  const float* query = (const float*)d_in[0];
  const float* key   = (const float*)d_in[1];
  const float* wq = (const float*)d_in[2];
  const float* bq = (const float*)d_in[3];
  const float* wk = (const float*)d_in[4];
  const float* bk = (const float*)d_in[5];
  const float* wv = (const float*)d_in[6];
  const float* bv = (const float*)d_in[7];
  const float* wo = (const float*)d_in[8];
  const float* bo = (const float*)d_in[9];

  char* ws = (char*)d_ws;
  unsigned short* Xq = (unsigned short*)(ws);               // 32 MiB
  unsigned short* Xk = (unsigned short*)(ws + 33554432);    // 32 MiB
  unsigned short* Wq = (unsigned short*)(ws + 67108864);    // 8 MiB
  unsigned short* Wk = (unsigned short*)(ws + 75497472);
  unsigned short* Wv = (unsigned short*)(ws + 83886080);
  unsigned short* Wo = (unsigned short*)(ws + 92274688);
  unsigned short* Qh = (unsigned short*)(ws + 100663296);   // 32 MiB (n,h,l,d)
  unsigned short* Kh = (unsigned short*)(ws + 134217728);   // 32 MiB (n,h,l,d)
  unsigned short* VT = (unsigned short*)(ws + 167772160);   // 32 MiB (n,h,d,l)
  unsigned short* Cc = Xq;  // context aliases Xq (Xq dead after Q-projection)

  const int nAct8 = L_SEQ * N_B * E_DIM / 8;  // 2,097,152
  const int nW8   = E_DIM * E_DIM / 8;        //   524,288
  cvt_kernel<<<dim3((nAct8 + 255) / 256), 256, 0, stream>>>(query, Xq, nAct8);
  cvt_kernel<<<dim3((nAct8 + 255) / 256), 256, 0, stream>>>(key, Xk, nAct8);
  cvt_kernel<<<dim3((nW8 + 255) / 256), 256, 0, stream>>>(wq, Wq, nW8);
  cvt_kernel<<<dim3((nW8 + 255) / 256), 256, 0, stream>>>(wk, Wk, nW8);
  cvt_kernel<<<dim3((nW8 + 255) / 256), 256, 0, stream>>>(wv, Wv, nW8);
  cvt_kernel<<<dim3((nW8 + 255) / 256), 256, 0, stream>>>(wo, Wo, nW8);

  dim3 gg(E_DIM / 128, (L_SEQ * N_B) / 128);  // (16, 64)
  gemm_bt<1><<<gg, 256, 0, stream>>>(Xq, Wq, bq, Qh);
  gemm_bt<1><<<gg, 256, 0, stream>>>(Xk, Wk, bk, Kh);
  gemm_bt<2><<<gg, 256, 0, stream>>>(Xk, Wv, bv, VT);

  // 1-D grid, XCD-locality swizzle (see kernel comment): 64 heads x 16 tq
  flash_attn<<<dim3(N_B * N_H * (L_SEQ / 128)), 512, 0, stream>>>(Qh, Kh, VT, Cc);

  gemm_bt<0><<<gg, 256, 0, stream>>>(Cc, Wo, bo, d_out);
}